// Round 6
// baseline (674.114 us; speedup 1.0000x reference)
//
#include <hip/hip_runtime.h>

#define B_N 8192
#define D_N 512
#define K_N 64
#define H_N 256
#define SC  4608   // K*K + D
#define R_T 32     // rows per block
#define NT  512    // 8 waves

typedef __attribute__((ext_vector_type(8))) short short8;
typedef __attribute__((ext_vector_type(4))) short short4v;
typedef __attribute__((ext_vector_type(4))) float f32x4;

__device__ __forceinline__ unsigned short f2bf(float f) {
  unsigned int u = __builtin_bit_cast(unsigned int, f);
  u += 0x7fff + ((u >> 16) & 1);      // RNE
  return (unsigned short)(u >> 16);
}
__device__ __forceinline__ float bf2f(unsigned short h) {
  unsigned int u = ((unsigned int)h) << 16;
  return __builtin_bit_cast(float, u);
}

// ---- workspace layout (bf16 elements), per layer ----
// W1T [256][512]  @ 0        (W1T[n][k] = W1[k][n])
// UT  [ 64][512]  @ 131072
// W2p [panelized] @ 163840   : idx = (((k*2+th)*16 + c)*64 + j)*8 + e
//                              value = W2[t][512+64k+j], t = th*128+(c>>2)*32+(c&3)*8+e
// W2bT[ 512][256] @ 1212416  (W2bT[n][t] = W2[t][n])
// VT  [ 512][ 64] @ 1343488
#define L_ELEMS 1376256

struct PrepParams {
  const float* W1[3]; const float* U[3]; const float* W2[3]; const float* V[3];
  short* ws;
};

__global__ __launch_bounds__(256) void prep_weights(PrepParams p) {
  const int y = blockIdx.y;           // 0..14
  const int l = y / 5, m = y - 5 * l;
  short* wsl = p.ws + (size_t)l * L_ELEMS;
  if (m == 2) {                       // W2p panelized
    const float* in = p.W2[l];
    short* out = wsl + 163840;
    const long total = 1048576;
    for (long e = (long)blockIdx.x * 256 + threadIdx.x; e < total;
         e += (long)gridDim.x * 256) {
      const int el = (int)(e & 7);
      const int j  = (int)((e >> 3) & 63);
      const int c  = (int)((e >> 9) & 15);
      const int th = (int)((e >> 13) & 1);
      const int k  = (int)(e >> 14);
      const int t  = th * 128 + (c >> 2) * 32 + (c & 3) * 8 + el;
      out[e] = (short)f2bf(in[(size_t)t * SC + 512 + 64 * k + j]);
    }
    return;
  }
  const float* in; short* out; int K, istride, ioff, kshift;
  switch (m) {
    case 0: in = p.W1[l]; out = wsl;           K = 512; istride = 256;  ioff = 0; kshift = 9; break;
    case 1: in = p.U[l];  out = wsl + 131072;  K = 512; istride = 64;   ioff = 0; kshift = 9; break;
    case 3: in = p.W2[l]; out = wsl + 1212416; K = 256; istride = 4608; ioff = 0; kshift = 8; break;
    default:in = p.V[l];  out = wsl + 1343488; K = 64;  istride = 512;  ioff = 0; kshift = 6; break;
  }
  const long total = (long)K * ((m == 0) ? 256 : (m == 1) ? 64 : (m == 3) ? 512 : 512);
  for (long e = (long)blockIdx.x * 256 + threadIdx.x; e < total;
       e += (long)gridDim.x * 256) {
    const int k = (int)(e & (K - 1));
    const int n = (int)(e >> kshift);
    out[e] = (short)f2bf(in[(size_t)k * istride + ioff + n]);
  }
}

struct Params {
  const float* x;
  const float* b1[3];
  const float* b2[3];
  const float* Wout;
  const float* bout;
  const short* ws;
  float* out;
};

#define XP 520   // xs pitch in shorts
#define HP 264
#define TP 72

__device__ __forceinline__ void stage_panel(const short* W2p, short* dst,
                                            int s, int w, int lane) {
#pragma unroll
  for (int i = 0; i < 2; ++i) {
    const short* gp = W2p + ((size_t)s << 13) + (w << 10) + (i << 9) + (lane << 3);
    short* lp = dst + (w << 10) + (i << 9);   // wave-uniform dest; HW adds lane*16B
    __builtin_amdgcn_global_load_lds(
        (const __attribute__((address_space(1))) void*)gp,
        (__attribute__((address_space(3))) void*)lp, 16, 0, 0);
  }
}

__global__ __launch_bounds__(NT, 1) void apg_mfma(Params p) {
  __shared__ __attribute__((aligned(16))) short pans[4][8192]; // 64 KB panel ring
  __shared__ short xs[R_T][XP];     // 33.3 KB
  __shared__ short h1s[R_T][HP];    // 16.9 KB
  __shared__ short tmps[R_T][TP];   //  4.6 KB
  __shared__ float hs[R_T][68];     //  8.7 KB  h = x@U, f32

  const int tid  = threadIdx.x;
  const int row0 = blockIdx.x * R_T;
  const int w    = tid >> 6;         // wave 0..7
  const int lane = tid & 63;
  const int l15  = tid & 15;
  const int g    = (tid & 63) >> 4;  // 0..3
  const int koff = g * 8;
  const int rh   = w >> 2;           // row-half 0/1
  const int rbase = rh * 16;

  // ---- load x tile -> bf16 LDS ----
  {
    const float4* xg = (const float4*)(p.x + (size_t)row0 * D_N);
    for (int i = tid; i < R_T * D_N / 4; i += NT) {
      float4 v = xg[i];
      const int r = i >> 7;
      const int c = (i & 127) << 2;
      short4v s4 = { (short)f2bf(v.x), (short)f2bf(v.y), (short)f2bf(v.z), (short)f2bf(v.w) };
      *(short4v*)&xs[r][c] = s4;
    }
  }
  __syncthreads();

  for (int l = 0; l < 3; ++l) {
    const short* wsl  = p.ws + (size_t)l * L_ELEMS;
    const short* W1T  = wsl;
    const short* UT   = wsl + 131072;
    const short* W2p  = wsl + 163840;
    const short* W2bT = wsl + 1212416;
    const short* VT   = wsl + 1343488;
    const float* b1 = p.b1[l];
    const float* b2 = p.b2[l];

    // ---- A-operand x fragments (rows rbase..rbase+16), kept for stages A+B ----
    short8 aX[16];
#pragma unroll
    for (int kk = 0; kk < 16; ++kk)
      aX[kk] = *(const short8*)&xs[rbase + l15][kk * 32 + koff];

    // ---- stage A: h1 = relu(x @ W1 + b1); wave -> 4 n-frags of its row-half ----
    for (int nf = 0; nf < 4; ++nf) {
      const int n0 = (((w & 3) << 2) + nf) << 4;
      const short* pb = W1T + ((size_t)(n0 + l15) << 9) + koff;
      short8 bf[16];
#pragma unroll
      for (int kk = 0; kk < 16; ++kk) bf[kk] = *(const short8*)(pb + kk * 32);
      f32x4 acc = {0.f, 0.f, 0.f, 0.f};
#pragma unroll
      for (int kk = 0; kk < 16; ++kk)
        acc = __builtin_amdgcn_mfma_f32_16x16x32_bf16(aX[kk], bf[kk], acc, 0, 0, 0);
      const float bb = b1[n0 + l15];
#pragma unroll
      for (int i = 0; i < 4; ++i)
        h1s[rbase + g * 4 + i][n0 + l15] = (short)f2bf(fmaxf(acc[i] + bb, 0.f));
    }

    // ---- stage B: h = x @ U (f32); wave -> n-frag (w&3), its row-half ----
    {
      const int n0 = (w & 3) << 4;
      const short* pb = UT + ((size_t)(n0 + l15) << 9) + koff;
      short8 bf[16];
#pragma unroll
      for (int kk = 0; kk < 16; ++kk) bf[kk] = *(const short8*)(pb + kk * 32);
      f32x4 acc = {0.f, 0.f, 0.f, 0.f};
#pragma unroll
      for (int kk = 0; kk < 16; ++kk)
        acc = __builtin_amdgcn_mfma_f32_16x16x32_bf16(aX[kk], bf[kk], acc, 0, 0, 0);
#pragma unroll
      for (int i = 0; i < 4; ++i) hs[rbase + g * 4 + i][n0 + l15] = acc[i];
    }
    __syncthreads();   // h1s, hs ready

    // ---- stage C: tmp[r][j] = sum_k h[r,k] * (h1@W2S + b2S)[r, 64k+j] ----
    // 128 16KB panels streamed through a 4-deep LDS ring via global_load_lds,
    // raw s_barrier + counted vmcnt (never 0 in steady state).
    {
      const int j0 = (w & 3) << 4;
      short8 aH[8];
#pragma unroll
      for (int kk = 0; kk < 8; ++kk)
        aH[kk] = *(const short8*)&h1s[rbase + l15][kk * 32 + koff];

      // tacc init: einsum-bias term sum_k h[r,k]*b2[512+64k+j]  (b2 == 0 here,
      // but computed for generality; outside the counted-vmcnt region)
      float tacc[4] = {0.f, 0.f, 0.f, 0.f};
      {
        const float* pb2 = b2 + D_N + j0 + l15;
#pragma unroll 4
        for (int k = 0; k < K_N; ++k) {
          const float b2v = pb2[k << 6];
#pragma unroll
          for (int i = 0; i < 4; ++i)
            tacc[i] += hs[rbase + g * 4 + i][k] * b2v;
        }
      }

      // prologue: panels 0,1,2 in flight
      stage_panel(W2p, &pans[0][0], 0, w, lane);
      stage_panel(W2p, &pans[1][0], 1, w, lane);
      stage_panel(W2p, &pans[2][0], 2, w, lane);

      f32x4 sacc = {0.f, 0.f, 0.f, 0.f};
#pragma unroll 1
      for (int s = 0; s < 128; ++s) {
        const int th = s & 1;
        const int k  = s >> 1;
        // wait: panel s complete (2 loads per panel per thread)
        if (s < 126)       asm volatile("s_waitcnt vmcnt(4)" ::: "memory");
        else if (s == 126) asm volatile("s_waitcnt vmcnt(2)" ::: "memory");
        else               asm volatile("s_waitcnt vmcnt(0)" ::: "memory");
        __builtin_amdgcn_s_barrier();   // all waves' panel-s loads done; all
                                        // phase s-1 reads of buf (s+3)&3 done
        if (s + 3 < 128) stage_panel(W2p, &pans[(s + 3) & 3][0], s + 3, w, lane);

        const short* pb = &pans[s & 3][0] + ((j0 + l15) << 3);
        if (th == 0) { f32x4 z = {0.f, 0.f, 0.f, 0.f}; sacc = z; }
#pragma unroll
        for (int kkl = 0; kkl < 4; ++kkl) {
          short8 bfrag = *(const short8*)(pb + ((kkl * 4 + g) << 9));
          sacc = __builtin_amdgcn_mfma_f32_16x16x32_bf16(aH[4 * th + kkl], bfrag, sacc, 0, 0, 0);
        }
        if (th == 1) {
#pragma unroll
          for (int i = 0; i < 4; ++i)
            tacc[i] += hs[rbase + g * 4 + i][k] * sacc[i];
        }
      }
#pragma unroll
      for (int i = 0; i < 4; ++i)
        tmps[rbase + g * 4 + i][j0 + l15] = (short)f2bf(tacc[i]);
    }
    __syncthreads();

    // ---- stage D: xnew = relu(tmp@V + h1@W2[:, :512] + b2[:512]) -> xs ----
    {
      short8 aT[2], aD[8];
#pragma unroll
      for (int kk = 0; kk < 2; ++kk)
        aT[kk] = *(const short8*)&tmps[rbase + l15][kk * 32 + koff];
#pragma unroll
      for (int kk = 0; kk < 8; ++kk)
        aD[kk] = *(const short8*)&h1s[rbase + l15][kk * 32 + koff];
      for (int ti = 0; ti < 8; ++ti) {
        const int n0 = ((ti << 2) + (w & 3)) << 4;
        const short* pv = VT + ((size_t)(n0 + l15) << 6) + koff;
        const short* pw = W2bT + ((size_t)(n0 + l15) << 8) + koff;
        short8 bv[2], bw[8];
#pragma unroll
        for (int kk = 0; kk < 2; ++kk) bv[kk] = *(const short8*)(pv + kk * 32);
#pragma unroll
        for (int kk = 0; kk < 8; ++kk) bw[kk] = *(const short8*)(pw + kk * 32);
        f32x4 acc = {0.f, 0.f, 0.f, 0.f};
#pragma unroll
        for (int kk = 0; kk < 2; ++kk)
          acc = __builtin_amdgcn_mfma_f32_16x16x32_bf16(aT[kk], bv[kk], acc, 0, 0, 0);
#pragma unroll
        for (int kk = 0; kk < 8; ++kk)
          acc = __builtin_amdgcn_mfma_f32_16x16x32_bf16(aD[kk], bw[kk], acc, 0, 0, 0);
        const float bb = b2[n0 + l15];
#pragma unroll
        for (int i = 0; i < 4; ++i)
          xs[rbase + g * 4 + i][n0 + l15] = (short)f2bf(fmaxf(acc[i] + bb, 0.f));
      }
    }
    __syncthreads();
  }

  // ---- out = x @ Wout + bout ----
  {
    const int r  = tid >> 4;
    const int cl = tid & 15;
    float acc = 0.f;
    for (int c = cl; c < D_N; c += 16)
      acc = fmaf(bf2f((unsigned short)xs[r][c]), p.Wout[c], acc);
#pragma unroll
    for (int s = 1; s < 16; s <<= 1) acc += __shfl_xor(acc, s, 64);
    if (cl == 0) p.out[row0 + r] = acc + p.bout[0];
  }
}

extern "C" void kernel_launch(void* const* d_in, const int* in_sizes, int n_in,
                              void* d_out, int out_size, void* d_ws, size_t ws_size,
                              hipStream_t stream) {
  (void)in_sizes; (void)n_in; (void)ws_size; (void)out_size;
  PrepParams pp;
  Params p;
  p.x = (const float*)d_in[0];
  for (int l = 0; l < 3; ++l) {
    const int base = 1 + l * 6;
    pp.U[l]  = (const float*)d_in[base + 0];
    pp.V[l]  = (const float*)d_in[base + 1];
    pp.W1[l] = (const float*)d_in[base + 2];
    p.b1[l]  = (const float*)d_in[base + 3];
    pp.W2[l] = (const float*)d_in[base + 4];
    p.b2[l]  = (const float*)d_in[base + 5];
  }
  p.Wout = (const float*)d_in[19];
  p.bout = (const float*)d_in[20];
  p.ws   = (const short*)d_ws;
  p.out  = (float*)d_out;
  pp.ws  = (short*)d_ws;

  hipLaunchKernelGGL(prep_weights, dim3(1024, 15), dim3(256), 0, stream, pp);
  hipLaunchKernelGGL(apg_mfma, dim3(B_N / R_T), dim3(NT), 0, stream, p);
}

// Round 7
// 333.655 us; speedup vs baseline: 2.0204x; 2.0204x over previous
//
#include <hip/hip_runtime.h>

#define B_N 8192
#define D_N 512
#define K_N 64
#define H_N 256
#define SC  4608   // K*K + D
#define R_T 32     // rows per block
#define NT  512    // 8 waves

typedef __attribute__((ext_vector_type(8))) short short8;
typedef __attribute__((ext_vector_type(4))) short short4v;
typedef __attribute__((ext_vector_type(4))) float f32x4;

__device__ __forceinline__ unsigned short f2bf(float f) {
  unsigned int u = __builtin_bit_cast(unsigned int, f);
  u += 0x7fff + ((u >> 16) & 1);      // RNE
  return (unsigned short)(u >> 16);
}
__device__ __forceinline__ float bf2f(unsigned short h) {
  unsigned int u = ((unsigned int)h) << 16;
  return __builtin_bit_cast(float, u);
}

// ---- workspace layout (bf16 elements), per layer ----
// W1T [256][512]  @ 0        (W1T[n][k] = W1[k][n])
// UT  [ 64][512]  @ 131072
// W2p [panelized] @ 163840   : idx = (((k*2+th)*16 + c)*64 + j)*8 + e
//                              value = W2[t][512+64k+j], t = th*128+(c>>2)*32+(c&3)*8+e
// W2bT[ 512][256] @ 1212416  (W2bT[n][t] = W2[t][n])
// VT  [ 512][ 64] @ 1343488
#define L_ELEMS 1376256

struct PrepParams {
  const float* W1[3]; const float* U[3]; const float* W2[3]; const float* V[3];
  short* ws;
};

__global__ __launch_bounds__(256) void prep_weights(PrepParams p) {
  const int y = blockIdx.y;           // 0..14
  const int l = y / 5, m = y - 5 * l;
  short* wsl = p.ws + (size_t)l * L_ELEMS;
  if (m == 2) {                       // W2p panelized
    const float* in = p.W2[l];
    short* out = wsl + 163840;
    const long total = 1048576;
    for (long e = (long)blockIdx.x * 256 + threadIdx.x; e < total;
         e += (long)gridDim.x * 256) {
      const int el = (int)(e & 7);
      const int j  = (int)((e >> 3) & 63);
      const int c  = (int)((e >> 9) & 15);
      const int th = (int)((e >> 13) & 1);
      const int k  = (int)(e >> 14);
      const int t  = th * 128 + (c >> 2) * 32 + (c & 3) * 8 + el;
      out[e] = (short)f2bf(in[(size_t)t * SC + 512 + 64 * k + j]);
    }
    return;
  }
  const float* in; short* out; int K, istride, ioff, kshift;
  switch (m) {
    case 0: in = p.W1[l]; out = wsl;           K = 512; istride = 256;  ioff = 0; kshift = 9; break;
    case 1: in = p.U[l];  out = wsl + 131072;  K = 512; istride = 64;   ioff = 0; kshift = 9; break;
    case 3: in = p.W2[l]; out = wsl + 1212416; K = 256; istride = 4608; ioff = 0; kshift = 8; break;
    default:in = p.V[l];  out = wsl + 1343488; K = 64;  istride = 512;  ioff = 0; kshift = 6; break;
  }
  const long total = (long)K * ((m == 0) ? 256 : (m == 1) ? 64 : (m == 3) ? 512 : 512);
  for (long e = (long)blockIdx.x * 256 + threadIdx.x; e < total;
       e += (long)gridDim.x * 256) {
    const int k = (int)(e & (K - 1));
    const int n = (int)(e >> kshift);
    out[e] = (short)f2bf(in[(size_t)k * istride + ioff + n]);
  }
}

struct Params {
  const float* x;
  const float* b1[3];
  const float* b2[3];
  const float* Wout;
  const float* bout;
  const short* ws;
  float* out;
};

#define XP 520   // xs pitch in shorts
#define HP 264
#define TP 72

__device__ __forceinline__ void stage_panel(const short* W2p, short* dst,
                                            int s, int w, int lane) {
#pragma unroll
  for (int i = 0; i < 2; ++i) {
    const short* gp = W2p + ((size_t)s << 13) + (w << 10) + (i << 9) + (lane << 3);
    short* lp = dst + (w << 10) + (i << 9);   // wave-uniform dest; HW adds lane*16B
    __builtin_amdgcn_global_load_lds(
        (const __attribute__((address_space(1))) void*)gp,
        (__attribute__((address_space(3))) void*)lp, 16, 0, 0);
  }
}

__global__ __launch_bounds__(NT, 1) void apg_mfma(Params p) {
  __shared__ __attribute__((aligned(16))) short pans[4][8192]; // 64 KB panel ring
  __shared__ short xs[R_T][XP];     // 33.3 KB
  __shared__ short h1s[R_T][HP];    // 16.9 KB
  __shared__ short tmps[R_T][TP];   //  4.6 KB
  __shared__ float hs[R_T][68];     //  8.7 KB  h = x@U, f32

  const int tid  = threadIdx.x;
  const int row0 = blockIdx.x * R_T;
  const int w    = tid >> 6;         // wave 0..7
  const int lane = tid & 63;
  const int l15  = tid & 15;
  const int g    = (tid & 63) >> 4;  // 0..3
  const int koff = g * 8;
  const int rh   = w >> 2;           // row-half 0/1
  const int rbase = rh * 16;

  // ---- load x tile -> bf16 LDS ----
  {
    const float4* xg = (const float4*)(p.x + (size_t)row0 * D_N);
    for (int i = tid; i < R_T * D_N / 4; i += NT) {
      float4 v = xg[i];
      const int r = i >> 7;
      const int c = (i & 127) << 2;
      short4v s4 = { (short)f2bf(v.x), (short)f2bf(v.y), (short)f2bf(v.z), (short)f2bf(v.w) };
      *(short4v*)&xs[r][c] = s4;
    }
  }
  __syncthreads();

  for (int l = 0; l < 3; ++l) {
    const short* wsl  = p.ws + (size_t)l * L_ELEMS;
    const short* W1T  = wsl;
    const short* UT   = wsl + 131072;
    const short* W2p  = wsl + 163840;
    const short* W2bT = wsl + 1212416;
    const short* VT   = wsl + 1343488;
    const float* b1 = p.b1[l];
    const float* b2 = p.b2[l];

    // ---- A-operand x fragments (rows rbase..rbase+16), kept for stages A+B ----
    short8 aX[16];
#pragma unroll
    for (int kk = 0; kk < 16; ++kk)
      aX[kk] = *(const short8*)&xs[rbase + l15][kk * 32 + koff];

    // ---- stage A: h1 = relu(x @ W1 + b1); wave -> 4 n-frags of its row-half ----
    for (int nf = 0; nf < 4; ++nf) {
      const int n0 = (((w & 3) << 2) + nf) << 4;
      const short* pb = W1T + ((size_t)(n0 + l15) << 9) + koff;
      short8 bf[16];
#pragma unroll
      for (int kk = 0; kk < 16; ++kk) bf[kk] = *(const short8*)(pb + kk * 32);
      f32x4 acc = {0.f, 0.f, 0.f, 0.f};
#pragma unroll
      for (int kk = 0; kk < 16; ++kk)
        acc = __builtin_amdgcn_mfma_f32_16x16x32_bf16(aX[kk], bf[kk], acc, 0, 0, 0);
      const float bb = b1[n0 + l15];
#pragma unroll
      for (int i = 0; i < 4; ++i)
        h1s[rbase + g * 4 + i][n0 + l15] = (short)f2bf(fmaxf(acc[i] + bb, 0.f));
    }

    // ---- stage B: h = x @ U (f32); wave -> n-frag (w&3), its row-half ----
    {
      const int n0 = (w & 3) << 4;
      const short* pb = UT + ((size_t)(n0 + l15) << 9) + koff;
      short8 bf[16];
#pragma unroll
      for (int kk = 0; kk < 16; ++kk) bf[kk] = *(const short8*)(pb + kk * 32);
      f32x4 acc = {0.f, 0.f, 0.f, 0.f};
#pragma unroll
      for (int kk = 0; kk < 16; ++kk)
        acc = __builtin_amdgcn_mfma_f32_16x16x32_bf16(aX[kk], bf[kk], acc, 0, 0, 0);
#pragma unroll
      for (int i = 0; i < 4; ++i) hs[rbase + g * 4 + i][n0 + l15] = acc[i];
    }
    __syncthreads();   // h1s, hs ready

    // ---- stage C: tmp[r][j] = sum_k h[r,k] * (h1@W2S + b2S)[r, 64k+j] ----
    // 128 16KB panels streamed through a 4-deep LDS ring via global_load_lds,
    // raw s_barrier + counted vmcnt; ALL register-array indices compile-time.
    {
      const int j0 = (w & 3) << 4;
      short8 aH[8];
#pragma unroll
      for (int kk = 0; kk < 8; ++kk)
        aH[kk] = *(const short8*)&h1s[rbase + l15][kk * 32 + koff];

      // tacc init: einsum-bias term sum_k h[r,k]*b2[512+64k+j]
      float tacc[4] = {0.f, 0.f, 0.f, 0.f};
      {
        const float* pb2 = b2 + D_N + j0 + l15;
#pragma unroll 4
        for (int k = 0; k < K_N; ++k) {
          const float b2v = pb2[k << 6];
#pragma unroll
          for (int i = 0; i < 4; ++i)
            tacc[i] += hs[rbase + g * 4 + i][k] * b2v;
        }
      }

      // drain any outstanding global loads so vmcnt counts only panel loads
      asm volatile("s_waitcnt vmcnt(0)" ::: "memory");
      // prologue: panels 0,1,2 in flight (2 loads each per thread)
      stage_panel(W2p, &pans[0][0], 0, w, lane);
      stage_panel(W2p, &pans[1][0], 1, w, lane);
      stage_panel(W2p, &pans[2][0], 2, w, lane);

      const int pbo = (j0 + l15) << 3;
      // steady state: k = 0..61, branch-free; static even/odd phases
#pragma unroll 1
      for (int k = 0; k < 62; ++k) {
        const int s0 = 2 * k;
        // even phase (th=0): panel s0, stage s0+3
        asm volatile("s_waitcnt vmcnt(4)" ::: "memory");
        __builtin_amdgcn_s_barrier();
        stage_panel(W2p, &pans[(s0 + 3) & 3][0], s0 + 3, w, lane);
        const short* pb0 = &pans[s0 & 3][0] + pbo;
        f32x4 sacc = {0.f, 0.f, 0.f, 0.f};
#pragma unroll
        for (int kkl = 0; kkl < 4; ++kkl) {
          short8 bfrag = *(const short8*)(pb0 + ((kkl * 4 + g) << 9));
          sacc = __builtin_amdgcn_mfma_f32_16x16x32_bf16(aH[kkl], bfrag, sacc, 0, 0, 0);
        }
        // odd phase (th=1): panel s0+1, stage s0+4
        asm volatile("s_waitcnt vmcnt(4)" ::: "memory");
        __builtin_amdgcn_s_barrier();
        stage_panel(W2p, &pans[(s0 + 4) & 3][0], s0 + 4, w, lane);
        const short* pb1 = &pans[(s0 + 1) & 3][0] + pbo;
#pragma unroll
        for (int kkl = 0; kkl < 4; ++kkl) {
          short8 bfrag = *(const short8*)(pb1 + ((kkl * 4 + g) << 9));
          sacc = __builtin_amdgcn_mfma_f32_16x16x32_bf16(aH[4 + kkl], bfrag, sacc, 0, 0, 0);
        }
#pragma unroll
        for (int i = 0; i < 4; ++i)
          tacc[i] += hs[rbase + g * 4 + i][k] * sacc[i];
      }
      // k = 62: panels 124,125; stage 127 in even phase only
      {
        asm volatile("s_waitcnt vmcnt(4)" ::: "memory");
        __builtin_amdgcn_s_barrier();
        stage_panel(W2p, &pans[127 & 3][0], 127, w, lane);
        const short* pb0 = &pans[124 & 3][0] + pbo;
        f32x4 sacc = {0.f, 0.f, 0.f, 0.f};
#pragma unroll
        for (int kkl = 0; kkl < 4; ++kkl) {
          short8 bfrag = *(const short8*)(pb0 + ((kkl * 4 + g) << 9));
          sacc = __builtin_amdgcn_mfma_f32_16x16x32_bf16(aH[kkl], bfrag, sacc, 0, 0, 0);
        }
        asm volatile("s_waitcnt vmcnt(4)" ::: "memory");
        __builtin_amdgcn_s_barrier();
        const short* pb1 = &pans[125 & 3][0] + pbo;
#pragma unroll
        for (int kkl = 0; kkl < 4; ++kkl) {
          short8 bfrag = *(const short8*)(pb1 + ((kkl * 4 + g) << 9));
          sacc = __builtin_amdgcn_mfma_f32_16x16x32_bf16(aH[4 + kkl], bfrag, sacc, 0, 0, 0);
        }
#pragma unroll
        for (int i = 0; i < 4; ++i)
          tacc[i] += hs[rbase + g * 4 + i][62] * sacc[i];
      }
      // k = 63: panels 126,127; drain
      {
        asm volatile("s_waitcnt vmcnt(2)" ::: "memory");
        __builtin_amdgcn_s_barrier();
        const short* pb0 = &pans[126 & 3][0] + pbo;
        f32x4 sacc = {0.f, 0.f, 0.f, 0.f};
#pragma unroll
        for (int kkl = 0; kkl < 4; ++kkl) {
          short8 bfrag = *(const short8*)(pb0 + ((kkl * 4 + g) << 9));
          sacc = __builtin_amdgcn_mfma_f32_16x16x32_bf16(aH[kkl], bfrag, sacc, 0, 0, 0);
        }
        asm volatile("s_waitcnt vmcnt(0)" ::: "memory");
        __builtin_amdgcn_s_barrier();
        const short* pb1 = &pans[127 & 3][0] + pbo;
#pragma unroll
        for (int kkl = 0; kkl < 4; ++kkl) {
          short8 bfrag = *(const short8*)(pb1 + ((kkl * 4 + g) << 9));
          sacc = __builtin_amdgcn_mfma_f32_16x16x32_bf16(aH[4 + kkl], bfrag, sacc, 0, 0, 0);
        }
#pragma unroll
        for (int i = 0; i < 4; ++i)
          tacc[i] += hs[rbase + g * 4 + i][63] * sacc[i];
      }
#pragma unroll
      for (int i = 0; i < 4; ++i)
        tmps[rbase + g * 4 + i][j0 + l15] = (short)f2bf(tacc[i]);
    }
    __syncthreads();

    // ---- stage D: xnew = relu(tmp@V + h1@W2[:, :512] + b2[:512]) -> xs ----
    {
      short8 aT[2], aD[8];
#pragma unroll
      for (int kk = 0; kk < 2; ++kk)
        aT[kk] = *(const short8*)&tmps[rbase + l15][kk * 32 + koff];
#pragma unroll
      for (int kk = 0; kk < 8; ++kk)
        aD[kk] = *(const short8*)&h1s[rbase + l15][kk * 32 + koff];
      for (int ti = 0; ti < 8; ++ti) {
        const int n0 = ((ti << 2) + (w & 3)) << 4;
        const short* pv = VT + ((size_t)(n0 + l15) << 6) + koff;
        const short* pw = W2bT + ((size_t)(n0 + l15) << 8) + koff;
        short8 bv[2], bw[8];
#pragma unroll
        for (int kk = 0; kk < 2; ++kk) bv[kk] = *(const short8*)(pv + kk * 32);
#pragma unroll
        for (int kk = 0; kk < 8; ++kk) bw[kk] = *(const short8*)(pw + kk * 32);
        f32x4 acc = {0.f, 0.f, 0.f, 0.f};
#pragma unroll
        for (int kk = 0; kk < 2; ++kk)
          acc = __builtin_amdgcn_mfma_f32_16x16x32_bf16(aT[kk], bv[kk], acc, 0, 0, 0);
#pragma unroll
        for (int kk = 0; kk < 8; ++kk)
          acc = __builtin_amdgcn_mfma_f32_16x16x32_bf16(aD[kk], bw[kk], acc, 0, 0, 0);
        const float bb = b2[n0 + l15];
#pragma unroll
        for (int i = 0; i < 4; ++i)
          xs[rbase + g * 4 + i][n0 + l15] = (short)f2bf(fmaxf(acc[i] + bb, 0.f));
      }
    }
    __syncthreads();
  }

  // ---- out = x @ Wout + bout ----
  {
    const int r  = tid >> 4;
    const int cl = tid & 15;
    float acc = 0.f;
    for (int c = cl; c < D_N; c += 16)
      acc = fmaf(bf2f((unsigned short)xs[r][c]), p.Wout[c], acc);
#pragma unroll
    for (int s = 1; s < 16; s <<= 1) acc += __shfl_xor(acc, s, 64);
    if (cl == 0) p.out[row0 + r] = acc + p.bout[0];
  }
}

extern "C" void kernel_launch(void* const* d_in, const int* in_sizes, int n_in,
                              void* d_out, int out_size, void* d_ws, size_t ws_size,
                              hipStream_t stream) {
  (void)in_sizes; (void)n_in; (void)ws_size; (void)out_size;
  PrepParams pp;
  Params p;
  p.x = (const float*)d_in[0];
  for (int l = 0; l < 3; ++l) {
    const int base = 1 + l * 6;
    pp.U[l]  = (const float*)d_in[base + 0];
    pp.V[l]  = (const float*)d_in[base + 1];
    pp.W1[l] = (const float*)d_in[base + 2];
    p.b1[l]  = (const float*)d_in[base + 3];
    pp.W2[l] = (const float*)d_in[base + 4];
    p.b2[l]  = (const float*)d_in[base + 5];
  }
  p.Wout = (const float*)d_in[19];
  p.bout = (const float*)d_in[20];
  p.ws   = (const short*)d_ws;
  p.out  = (float*)d_out;
  pp.ws  = (short*)d_ws;

  hipLaunchKernelGGL(prep_weights, dim3(1024, 15), dim3(256), 0, stream, pp);
  hipLaunchKernelGGL(apg_mfma, dim3(B_N / R_T), dim3(NT), 0, stream, p);
}